// Round 1
// baseline (117.720 us; speedup 1.0000x reference)
//
#include <hip/hip_runtime.h>

// Problem constants
#define B_    16
#define A_    3
#define C_    80
#define H_    52
#define W_    52
#define T_    50
#define NLOC  (B_*H_*W_*A_)          // 129792 locations (B,H,W,A)
#define NPRED (B_*A_*(5+C_)*H_*W_)   // 11031040 prediction elements
#define PLANE (H_*W_)                // 2704
#define BSTRIDE (A_*(5+C_)*PLANE)    // 689520 elements per batch image
#define NB_MAIN 1024
#define NCOMP 9
// acc components: 0=sx 1=sy 2=sw 3=sh 4=sconf_obj 5=sconf_noobj 6=scls 7=npos 8=nnoobj

__device__ __forceinline__ float sigf(float x){ return 1.0f/(1.0f+__expf(-x)); }
__device__ __forceinline__ float clipp(float p){ return fminf(fmaxf(p, 1e-7f), 1.0f-1e-7f); }

__global__ void init_maps(float* __restrict__ obj, float* __restrict__ noobj,
                          int* __restrict__ winner){
    int i = blockIdx.x*blockDim.x + threadIdx.x;
    if (i < NLOC){ obj[i]=0.0f; noobj[i]=1.0f; winner[i]=-1; }
}

// Single block; two phases with syncthreads. Last-write-wins in flattened
// (b*T+t) order via atomicMax on winner[], matching numpy scatter-set.
__global__ void build_targets(const float* __restrict__ tgt,
                              float* __restrict__ obj, float* __restrict__ noobj,
                              float* __restrict__ tx, float* __restrict__ ty,
                              float* __restrict__ tw, float* __restrict__ th,
                              int* __restrict__ winner){
    const float AW[3]={14.5f,19.5f,46.625f};   // 116/8, 156/8, 373/8
    const float AH[3]={11.25f,24.75f,40.75f};  //  90/8, 198/8, 326/8
    int i = threadIdx.x;           // 0..831, targets are 0..799
    bool valid = false; int loc = 0;
    float vtx=0.f, vty=0.f, vtw=0.f, vth=0.f;
    if (i < B_*T_){
        int b = i / T_;
        const float* r = tgt + i*5;
        float s = r[0]+r[1]+r[2]+r[3]+r[4];
        if (s > 0.0f){
            valid = true;
            float gx = r[1]*(float)W_, gy = r[2]*(float)H_;
            float gw = r[3]*(float)W_, gh = r[4]*(float)H_;
            int gi = (int)gx, gj = (int)gy;
            float ious[3]; int best = 0; float best_iou = -1.0f;
            #pragma unroll
            for (int a=0;a<3;a++){
                float inter = fminf(gw, AW[a]) * fminf(gh, AH[a]);
                float iou = inter / (gw*gh + AW[a]*AH[a] - inter + 1e-16f);
                ious[a] = iou;
                if (iou > best_iou){ best_iou = iou; best = a; }  // first max wins ties (argmax)
            }
            int cell = (b*H_ + gi)*W_ + gj;   // NOTE: gi (from x) indexes H — reference quirk
            loc = cell*A_ + best;
            obj[loc] = 1.0f;                  // benign race: all write 1.0
            #pragma unroll
            for (int a=0;a<3;a++)
                if (ious[a] > 0.5f) noobj[cell*A_ + a] = 0.0f;  // benign race: all write 0.0
            atomicMax(&winner[loc], i);
            vtx = gx - (float)gi;  vty = gy - (float)gj;
            vtw = logf(gw/AW[best] + 1e-16f);
            vth = logf(gh/AH[best] + 1e-16f);
        }
    }
    __syncthreads();
    if (valid && winner[loc] == i){
        tx[loc]=vtx; ty[loc]=vty; tw[loc]=vtw; th[loc]=vth;
    }
}

// Fused sigmoid + BCE/MSE reduction over all prediction elements.
// "Both-zero" BCE cells contribute the constant -log(1-1e-7); handled
// analytically in finalize via counts (acc 7,8). tclas*m0 == 0 identically,
// so class loss = sum over obj==0 of -log(1-clip(sigmoid(p))).
__global__ __launch_bounds__(256) void main_reduce(
        const float4* __restrict__ pred4,
        const float* __restrict__ obj, const float* __restrict__ noobj,
        const float* __restrict__ tx, const float* __restrict__ ty,
        const float* __restrict__ tw, const float* __restrict__ th,
        float* __restrict__ partial){
    float acc[NCOMP];
    #pragma unroll
    for (int k=0;k<NCOMP;k++) acc[k]=0.0f;

    const int total4 = NPRED/4;
    for (int u = blockIdx.x*blockDim.x + threadIdx.x; u < total4;
         u += gridDim.x*blockDim.x){
        int e   = u*4;
        int b   = e / BSTRIDE;
        int r   = e - b*BSTRIDE;
        int c   = r / PLANE;
        int hw0 = r - c*PLANE;       // multiple of 4; stays within one channel plane
        int a   = c / 85;
        int f   = c - a*85;
        float4 v4 = pred4[u];
        float vv[4] = {v4.x, v4.y, v4.z, v4.w};
        #pragma unroll
        for (int k=0;k<4;k++){
            int hw = hw0 + k;
            int h = hw / W_; int w = hw - h*W_;
            int loc = ((b*H_ + h)*W_ + w)*A_ + a;
            float ob = obj[loc];
            float v  = vv[k];
            if (f >= 5){                       // class (80/85 of elements)
                if (ob == 0.0f){
                    float p = clipp(sigf(v));
                    acc[6] -= __logf(1.0f - p);
                }
            } else if (f == 4){                // conf
                float p = clipp(sigf(v));
                if (ob != 0.0f) acc[4] -= __logf(p);
                float nb = noobj[loc];
                if (nb != 0.0f) acc[5] -= __logf(1.0f - p);
                acc[7] += ob; acc[8] += nb;    // each loc counted exactly once (f==4)
            } else if (f < 2){                 // x,y : BCE(sigmoid, txy)
                if (ob != 0.0f){
                    float p = clipp(sigf(v));
                    float t = (f==0) ? tx[loc] : ty[loc];
                    acc[f] -= t*__logf(p) + (1.0f-t)*__logf(1.0f-p);
                }
            } else {                           // w,h : MSE(raw, twh)
                if (ob != 0.0f){
                    float t = (f==2) ? tw[loc] : th[loc];
                    float d = v - t;
                    acc[f] += d*d;
                }
            }
        }
    }

    // wave (64) shuffle reduce, then cross-wave via LDS
    #pragma unroll
    for (int k=0;k<NCOMP;k++)
        for (int off=32; off; off>>=1)
            acc[k] += __shfl_down(acc[k], off, 64);
    __shared__ float lds[4][NCOMP];
    int lane = threadIdx.x & 63, wv = threadIdx.x >> 6;
    if (lane == 0){
        #pragma unroll
        for (int k=0;k<NCOMP;k++) lds[wv][k] = acc[k];
    }
    __syncthreads();
    if (threadIdx.x < NCOMP){
        float s = lds[0][threadIdx.x] + lds[1][threadIdx.x]
                + lds[2][threadIdx.x] + lds[3][threadIdx.x];
        partial[threadIdx.x*NB_MAIN + blockIdx.x] = s;  // comp-major for coalesced finalize
    }
}

__global__ void finalize(const float* __restrict__ partial, float* __restrict__ out){
    __shared__ float red[256];
    __shared__ float comp[NCOMP];
    int t = threadIdx.x;
    for (int k=0;k<NCOMP;k++){
        float s = 0.0f;
        for (int i=t; i<NB_MAIN; i+=256) s += partial[k*NB_MAIN + i];
        red[t] = s; __syncthreads();
        for (int st=128; st; st>>=1){ if (t<st) red[t]+=red[t+st]; __syncthreads(); }
        if (t==0) comp[k] = red[0];
        __syncthreads();
    }
    if (t == 0){
        const float Nf = (float)NLOC;
        float bce00 = -logf(1.0f - 1e-7f);   // BCE(clip(0),0) constant
        float npos = comp[7], nnoobj = comp[8];
        float lx = (comp[0] + (Nf-npos)*bce00)/Nf;
        float ly = (comp[1] + (Nf-npos)*bce00)/Nf;
        float lw = comp[2]/Nf;
        float lh = comp[3]/Nf;
        float lconf = (comp[4] + (Nf-npos)*bce00)/Nf
                    + 0.5f*((comp[5] + (Nf-nnoobj)*bce00)/Nf);
        float lcls = comp[6] / ((Nf-npos)*(float)C_);
        float loss = 2.5f*lx + 2.5f*ly + 2.5f*lw + 2.5f*lh + 1.0f*lconf + 1.0f*lcls;
        out[0]=loss; out[1]=lx; out[2]=ly; out[3]=lw; out[4]=lh; out[5]=lconf; out[6]=lcls;
    }
}

extern "C" void kernel_launch(void* const* d_in, const int* in_sizes, int n_in,
                              void* d_out, int out_size, void* d_ws, size_t ws_size,
                              hipStream_t stream) {
    const float* pred = (const float*)d_in[0];   // (16,255,52,52) f32
    const float* tgt  = (const float*)d_in[1];   // (16,50,5) f32

    float* ws   = (float*)d_ws;   // ~3.7 MB used
    float* obj  = ws;
    float* nob  = obj + NLOC;
    float* tx   = nob + NLOC;
    float* ty   = tx  + NLOC;
    float* tw   = ty  + NLOC;
    float* th   = tw  + NLOC;
    int*   win  = (int*)(th + NLOC);
    float* part = (float*)(win + NLOC);          // NCOMP * NB_MAIN floats

    init_maps<<<(NLOC+255)/256, 256, 0, stream>>>(obj, nob, win);
    build_targets<<<1, 832, 0, stream>>>(tgt, obj, nob, tx, ty, tw, th, win);
    main_reduce<<<NB_MAIN, 256, 0, stream>>>((const float4*)pred,
                                             obj, nob, tx, ty, tw, th, part);
    finalize<<<1, 256, 0, stream>>>(part, (float*)d_out);
}